// Round 1
// baseline (10.816 us; speedup 1.0000x reference)
//
#include <hip/hip_runtime.h>

// Problem constants (match reference):
//   B=16, T=4096, D=256, W=512
//   out[b, w, 0:256]   = x_fwd[b, m_fwd[b,w],  :]   (m = idx if idx>=2 else 0)
//   out[b, w, 256:512] = x_bwd[b, m_back[b,w], :]
// Output dtype: float32, shape (B, W, 2D) flat = 4,194,304 floats = 1,048,576 float4.

#define BB 16
#define TT 4096
#define DD 256
#define WW 512

// 128 float4 per output row (512 floats); 64 from fwd, 64 from bwd.
// total float4 = B*W*128 = 1,048,576 -> grid 4096 x block 256, 1 float4/thread.
__global__ __launch_bounds__(256) void gather_concat_kernel(
    const float* __restrict__ x_fwd,
    const float* __restrict__ x_bwd,
    const int* __restrict__ idx_fwd,
    const int* __restrict__ idx_back,
    float4* __restrict__ out)
{
    const int i = blockIdx.x * blockDim.x + threadIdx.x;  // float4 index
    const int d4  = i & 127;        // which float4 within the 2D-row
    const int row = i >> 7;         // b*W + w
    const int w   = row & (WW - 1);
    const int b   = row >> 9;       // W=512 -> shift 9

    // Wave-uniform half selection: lanes 0..63 of a wave share d4-range.
    const float4* src;
    int t, d4l;
    if (d4 < 64) {
        t   = idx_fwd[b * WW + w];
        src = reinterpret_cast<const float4*>(x_fwd);
        d4l = d4;
    } else {
        t   = idx_back[b * WW + w];
        src = reinterpret_cast<const float4*>(x_bwd);
        d4l = d4 - 64;
    }
    if (t < 2) t = 0;  // reference: idx * (idx >= 2)

    // row (b, t) of x: 256 floats = 64 float4
    out[i] = src[((size_t)b * TT + (size_t)t) * 64 + d4l];
}

extern "C" void kernel_launch(void* const* d_in, const int* in_sizes, int n_in,
                              void* d_out, int out_size, void* d_ws, size_t ws_size,
                              hipStream_t stream) {
    const float* x_fwd    = (const float*)d_in[0];
    const float* x_bwd    = (const float*)d_in[1];
    const int*   idx_fwd  = (const int*)d_in[2];
    const int*   idx_back = (const int*)d_in[3];
    float4*      out      = (float4*)d_out;

    const int total_f4 = BB * WW * 128;  // 1,048,576
    const int block = 256;
    const int grid = total_f4 / block;   // 4096
    gather_concat_kernel<<<grid, block, 0, stream>>>(x_fwd, x_bwd, idx_fwd, idx_back, out);
}

// Round 3
// 10.281 us; speedup vs baseline: 1.0520x; 1.0520x over previous
//
#include <hip/hip_runtime.h>

// Problem constants (match reference):
//   B=16, T=4096, D=256, W=512
//   out[b, w, 0:256]   = x_fwd[b, m_fwd[b,w],  :]   (m = idx if idx>=2 else 0)
//   out[b, w, 256:512] = x_bwd[b, m_back[b,w], :]
// Output: float32 (B, W, 2D) = 4,194,304 floats = 16 MiB.
//
// Layout: one thread handles ONE lane-position (float4) in BOTH halves of an
// output row. 64 lanes (one wave) = one full output row (128 float4).
//   - idx loads are wave-uniform broadcasts (one address per wave).
//   - gathered reads: 64 lanes x 16 B = contiguous 1 KiB row segment, coalesced.
//   - stores: two coalesced 1 KiB segments per wave, nontemporal (stream past
//     L2/L3 so the 128 MiB of inputs stay resident in Infinity Cache).
//
// NOTE: __builtin_nontemporal_store requires a native vector type, not HIP's
// float4 class -> use clang ext_vector_type(4).

#define BB 16
#define TT 4096
#define DD 256
#define WW 512

typedef float f4 __attribute__((ext_vector_type(4)));

__global__ __launch_bounds__(256) void gather_concat_kernel(
    const f4* __restrict__ x_fwd,
    const f4* __restrict__ x_bwd,
    const int* __restrict__ idx_fwd,
    const int* __restrict__ idx_back,
    f4* __restrict__ out)
{
    const int i   = blockIdx.x * 256 + threadIdx.x;  // [0, B*W*64)
    const int d4  = i & 63;          // float4 position within a D-row (64 per row)
    const int row = i >> 6;          // b*W + w in [0, 8192)
    const int b   = row >> 9;        // W = 512

    int tf = idx_fwd[row];
    int tb = idx_back[row];
    if (tf < 2) tf = 0;              // reference: idx * (idx >= 2)
    if (tb < 2) tb = 0;

    const size_t base = (size_t)b * TT * 64;         // f4 offset of batch b
    const f4 vf = x_fwd[base + (size_t)tf * 64 + d4];
    const f4 vb = x_bwd[base + (size_t)tb * 64 + d4];

    f4* o = out + (size_t)row * 128 + d4;
    __builtin_nontemporal_store(vf, o);
    __builtin_nontemporal_store(vb, o + 64);
}

extern "C" void kernel_launch(void* const* d_in, const int* in_sizes, int n_in,
                              void* d_out, int out_size, void* d_ws, size_t ws_size,
                              hipStream_t stream) {
    const f4*  x_fwd    = (const f4*)d_in[0];
    const f4*  x_bwd    = (const f4*)d_in[1];
    const int* idx_fwd  = (const int*)d_in[2];
    const int* idx_back = (const int*)d_in[3];
    f4*        out      = (f4*)d_out;

    const int total_threads = BB * WW * 64;  // 524,288
    const int block = 256;
    const int grid = total_threads / block;  // 2048
    gather_concat_kernel<<<grid, block, 0, stream>>>(x_fwd, x_bwd, idx_fwd, idx_back, out);
}